// Round 5
// baseline (936.160 us; speedup 1.0000x reference)
//
#include <hip/hip_runtime.h>
#include <cstdint>

typedef unsigned short u16;
typedef __attribute__((ext_vector_type(8))) short short8;   // 8 bf16 in 4 VGPRs (MFMA A/B frag)
typedef __attribute__((ext_vector_type(4))) float floatx4;  // MFMA C/D frag

__device__ __forceinline__ float b2f(u16 u) {
    union { unsigned int i; float f; } c; c.i = ((unsigned int)u) << 16; return c.f;
}
__device__ __forceinline__ u16 f2b(float f) {
    union { float f; unsigned int i; } c; c.f = f;
    unsigned int u = c.i;
    u = u + 0x7FFFu + ((u >> 16) & 1u);   // RNE
    return (u16)(u >> 16);
}
// tanh-gelu via exp2; max err vs exact erf-gelu ~3e-4
__device__ __forceinline__ float gelu_f(float x) {
    float u = x * x;
    float z = x * __builtin_fmaf(u, 0.1029432f, 2.3022082f);
    float t = __builtin_amdgcn_exp2f(z);
    float r = __builtin_amdgcn_rcpf(1.0f + t);
    return __builtin_fmaf(-x, r, x);
}

// ---------------------------------------------------------------------------
// GEMM: Y[m,n] = sum_k A[m,k]*W[n,k] + bias[n].  M=2048, N=512, K=512.
// A,W,bias fp32 (converted to bf16 in staging for MFMA).
// mode 0..2: store bf16 in (b,h,c,dd) layout (q/k/v)
// mode 3:    store fp32 plain [m*512+n]     (final output)
// ---------------------------------------------------------------------------
__global__ __launch_bounds__(256) void gemm_qkvo(
    const float* __restrict__ A, const float* __restrict__ W, const float* __restrict__ bias,
    u16* __restrict__ outb, float* __restrict__ outf, int mode)
{
    __shared__ u16 xs[64 * 72];   // +8 bf16 pad: 16B-aligned rows, breaks bank conflicts
    __shared__ u16 wsl[64 * 72];
    int tid = threadIdx.x;
    int lane = tid & 63;
    int wv = tid >> 6;
    int lo = lane & 15, hi = lane >> 4;
    int m0 = blockIdx.x * 64, n0 = blockIdx.y * 64;

    floatx4 acc[4];
#pragma unroll
    for (int mt = 0; mt < 4; ++mt) acc[mt] = (floatx4){0.f, 0.f, 0.f, 0.f};

    for (int k0 = 0; k0 < 512; k0 += 64) {
        __syncthreads();
#pragma unroll
        for (int i = 0; i < 2; ++i) {
            int v = tid + i * 256;
            int row = v >> 3, c8 = (v & 7) * 8;
            const float* ap = A + (m0 + row) * 512 + k0 + c8;
            const float* wp = W + (n0 + row) * 512 + k0 + c8;
            float4 a0 = *(const float4*)(ap);
            float4 a1 = *(const float4*)(ap + 4);
            float4 w0 = *(const float4*)(wp);
            float4 w1v = *(const float4*)(wp + 4);
            union { u16 u[8]; uint4 q; } ca, cw;
            ca.u[0] = f2b(a0.x); ca.u[1] = f2b(a0.y); ca.u[2] = f2b(a0.z); ca.u[3] = f2b(a0.w);
            ca.u[4] = f2b(a1.x); ca.u[5] = f2b(a1.y); ca.u[6] = f2b(a1.z); ca.u[7] = f2b(a1.w);
            cw.u[0] = f2b(w0.x); cw.u[1] = f2b(w0.y); cw.u[2] = f2b(w0.z); cw.u[3] = f2b(w0.w);
            cw.u[4] = f2b(w1v.x); cw.u[5] = f2b(w1v.y); cw.u[6] = f2b(w1v.z); cw.u[7] = f2b(w1v.w);
            *(uint4*)(xs + row * 72 + c8)  = ca.q;
            *(uint4*)(wsl + row * 72 + c8) = cw.q;
        }
        __syncthreads();
#pragma unroll
        for (int ks = 0; ks < 2; ++ks) {
            short8 bfr = *(const short8*)(wsl + (wv * 16 + lo) * 72 + ks * 32 + hi * 8);
#pragma unroll
            for (int mt = 0; mt < 4; ++mt) {
                short8 afr = *(const short8*)(xs + (mt * 16 + lo) * 72 + ks * 32 + hi * 8);
                acc[mt] = __builtin_amdgcn_mfma_f32_16x16x32_bf16(afr, bfr, acc[mt], 0, 0, 0);
            }
        }
    }

    int n = n0 + wv * 16 + lo;
    float bv = bias[n];
    int h = n >> 6, dd = n & 63;
#pragma unroll
    for (int mt = 0; mt < 4; ++mt) {
#pragma unroll
        for (int r = 0; r < 4; ++r) {
            int m = m0 + mt * 16 + hi * 4 + r;      // D layout: row=(lane>>4)*4+reg, col=lane&15
            float y = acc[mt][r] + bv;
            if (mode == 3) {
                outf[m * 512 + n] = y;              // fp32 final output
            } else {
                int b = m >> 10, c = m & 1023;
                outb[(((b * 8 + h) * 1024) + c) * 64 + dd] = f2b(y);
            }
        }
    }
}

// ---------------------------------------------------------------------------
// Fused second-order attention. 1 wave = 1 query, 4 queries (same b,h) per block.
// hid[j,e] = (qp[i,e]+b1[e]) + sum_dd k[j,dd] * (q[i,dd]*w1qk[e,dd] + w1k[e,dd])
//            (kp folded into the MFMA B-operand; acc initialized with qp+b1)
// scores scaled by 0.125*log2(e) folded into w2; b2 dropped (softmax-invariant).
// Online softmax over all 1024 keys, 32 keys per LDS-staged step.
// ---------------------------------------------------------------------------
__global__ __launch_bounds__(256) void attn_kernel(
    const u16* __restrict__ qb, const u16* __restrict__ kb, const u16* __restrict__ vb,
    const float* __restrict__ w1, const float* __restrict__ b1, const float* __restrict__ w2,
    float* __restrict__ ao)
{
    __shared__ u16  k_l[32 * 72];
    __shared__ float v_l[32 * 64];
    __shared__ float q_l[4 * 64];
    int tid = threadIdx.x;
    int lane = tid & 63;
    int wv = tid >> 6;
    int lo = lane & 15, hi = lane >> 4;
    int bh = blockIdx.x >> 8;                      // 0..15
    int qi = ((blockIdx.x & 255) << 2) | wv;       // query 0..1023

    q_l[wv * 64 + lane] = b2f(qb[(bh * 1024 + qi) * 64 + lane]);

    // qp[e] + b1[e], lane = e
    float qpacc = b1[lane];
#pragma unroll
    for (int d8 = 0; d8 < 64; d8 += 8) {
        float4 wa = *(const float4*)(w1 + lane * 192 + d8);
        float4 wb = *(const float4*)(w1 + lane * 192 + d8 + 4);
        const float* q8 = q_l + wv * 64 + d8;
        qpacc = __builtin_fmaf(q8[0], wa.x, qpacc);
        qpacc = __builtin_fmaf(q8[1], wa.y, qpacc);
        qpacc = __builtin_fmaf(q8[2], wa.z, qpacc);
        qpacc = __builtin_fmaf(q8[3], wa.w, qpacc);
        qpacc = __builtin_fmaf(q8[4], wb.x, qpacc);
        qpacc = __builtin_fmaf(q8[5], wb.y, qpacc);
        qpacc = __builtin_fmaf(q8[6], wb.z, qpacc);
        qpacc = __builtin_fmaf(q8[7], wb.w, qpacc);
    }
    float qpb[4], w2e[4];
#pragma unroll
    for (int t = 0; t < 4; ++t) {
        qpb[t] = __shfl(qpacc, t * 16 + lo);
        w2e[t] = w2[t * 16 + lo] * 0.18033688f;   // *(1/8)*log2(e)
    }

    // B-operand frags qw'[e,dd] = q[dd]*w1qk[e,dd] + w1k[e,dd], bf16
    short8 bfr[4][2];
#pragma unroll
    for (int t = 0; t < 4; ++t) {
#pragma unroll
        for (int ks = 0; ks < 2; ++ks) {
            int e = t * 16 + lo, dd0 = ks * 32 + hi * 8;
            float4 qk0 = *(const float4*)(w1 + e * 192 + 128 + dd0);
            float4 qk1 = *(const float4*)(w1 + e * 192 + 128 + dd0 + 4);
            float4 kk0 = *(const float4*)(w1 + e * 192 + 64 + dd0);
            float4 kk1 = *(const float4*)(w1 + e * 192 + 64 + dd0 + 4);
            const float* q8 = q_l + wv * 64 + dd0;
            union { u16 u[8]; short8 s; } cv;
            cv.u[0] = f2b(__builtin_fmaf(q8[0], qk0.x, kk0.x));
            cv.u[1] = f2b(__builtin_fmaf(q8[1], qk0.y, kk0.y));
            cv.u[2] = f2b(__builtin_fmaf(q8[2], qk0.z, kk0.z));
            cv.u[3] = f2b(__builtin_fmaf(q8[3], qk0.w, kk0.w));
            cv.u[4] = f2b(__builtin_fmaf(q8[4], qk1.x, kk1.x));
            cv.u[5] = f2b(__builtin_fmaf(q8[5], qk1.y, kk1.y));
            cv.u[6] = f2b(__builtin_fmaf(q8[6], qk1.z, kk1.z));
            cv.u[7] = f2b(__builtin_fmaf(q8[7], qk1.w, kk1.w));
            bfr[t][ks] = cv.s;
        }
    }

    float m_run = -1e30f, l_run = 0.f, oacc = 0.f;
    const u16* kbase = kb + bh * 65536;
    const u16* vbase = vb + bh * 65536;

    for (int j0 = 0; j0 < 1024; j0 += 32) {
        __syncthreads();
        {   // stage k tile (32x64 bf16) + v tile (32x64 bf16 -> f32 LDS)
            int row = tid >> 3, c8 = (tid & 7) * 8;
            *(uint4*)(k_l + row * 72 + c8) = *(const uint4*)(kbase + (j0 + row) * 64 + c8);
            uint4 vv4 = *(const uint4*)(vbase + (j0 + row) * 64 + c8);
            const u16* vu = (const u16*)&vv4;
            union { float f[4]; float4 v; } p0, p1;
#pragma unroll
            for (int j = 0; j < 4; ++j) { p0.f[j] = b2f(vu[j]); p1.f[j] = b2f(vu[4 + j]); }
            *(float4*)(v_l + row * 64 + c8)     = p0.v;
            *(float4*)(v_l + row * 64 + c8 + 4) = p1.v;
        }
        __syncthreads();

        floatx4 acc[2][4];
#pragma unroll
        for (int mt = 0; mt < 2; ++mt)
#pragma unroll
            for (int t = 0; t < 4; ++t)
                acc[mt][t] = (floatx4){qpb[t], qpb[t], qpb[t], qpb[t]};
#pragma unroll
        for (int mt = 0; mt < 2; ++mt) {
#pragma unroll
            for (int ks = 0; ks < 2; ++ks) {
                short8 afr = *(const short8*)(k_l + (mt * 16 + lo) * 72 + ks * 32 + hi * 8);
#pragma unroll
                for (int t = 0; t < 4; ++t)
                    acc[mt][t] = __builtin_amdgcn_mfma_f32_16x16x32_bf16(afr, bfr[t][ks], acc[mt][t], 0, 0, 0);
            }
        }

        // gelu + dot with w2, reduce over e (16 lanes of lo + 4 reg-tiles in-lane)
        float p[2][4];
        float tmax = -1e30f;
#pragma unroll
        for (int mt = 0; mt < 2; ++mt) {
#pragma unroll
            for (int r = 0; r < 4; ++r) {
                float s = 0.f;
#pragma unroll
                for (int t = 0; t < 4; ++t)
                    s = __builtin_fmaf(gelu_f(acc[mt][t][r]), w2e[t], s);
                s += __shfl_xor(s, 1);
                s += __shfl_xor(s, 2);
                s += __shfl_xor(s, 4);
                s += __shfl_xor(s, 8);
                p[mt][r] = s;                 // score (log2e-scaled), replicated in 16-lane group
                tmax = fmaxf(tmax, s);
            }
        }
        tmax = fmaxf(tmax, __shfl_xor(tmax, 16));
        tmax = fmaxf(tmax, __shfl_xor(tmax, 32));
        float m_new = fmaxf(m_run, tmax);
        float alpha = __builtin_amdgcn_exp2f(m_run - m_new);
        float ls = 0.f;
#pragma unroll
        for (int mt = 0; mt < 2; ++mt)
#pragma unroll
            for (int r = 0; r < 4; ++r) {
                p[mt][r] = __builtin_amdgcn_exp2f(p[mt][r] - m_new);
                ls += p[mt][r];
            }
        ls += __shfl_xor(ls, 16);
        ls += __shfl_xor(ls, 32);
        l_run = __builtin_fmaf(l_run, alpha, ls);
        oacc *= alpha;
        m_run = m_new;

        // PV: out[lane] += p_j * v[j,lane]; p for j = mt*16+g*4+r lives in lane-group g
#pragma unroll
        for (int mt = 0; mt < 2; ++mt)
#pragma unroll
            for (int g = 0; g < 4; ++g)
#pragma unroll
                for (int r = 0; r < 4; ++r) {
                    float pj = __shfl(p[mt][r], g * 16);
                    oacc = __builtin_fmaf(pj, v_l[(mt * 16 + g * 4 + r) * 64 + lane], oacc);
                }
    }

    float outv = oacc * __builtin_amdgcn_rcpf(l_run);
    int b = bh >> 3, h = bh & 7;
    ao[(b * 1024 + qi) * 512 + h * 64 + lane] = outv;   // (b, c, h*64+d) = (B,C,D) fp32
}

// ---------------------------------------------------------------------------
extern "C" void kernel_launch(void* const* d_in, const int* in_sizes, int n_in,
                              void* d_out, int out_size, void* d_ws, size_t ws_size,
                              hipStream_t stream)
{
    (void)in_sizes; (void)n_in; (void)out_size; (void)ws_size;
    const float* x  = (const float*)d_in[0];
    const float* Wq = (const float*)d_in[1];
    const float* bq = (const float*)d_in[2];
    const float* Wk = (const float*)d_in[3];
    const float* bk = (const float*)d_in[4];
    const float* Wv = (const float*)d_in[5];
    const float* bv = (const float*)d_in[6];
    const float* w1 = (const float*)d_in[7];
    const float* b1 = (const float*)d_in[8];
    const float* w2 = (const float*)d_in[9];
    // d_in[10] = b2: scalar shift of all scores -> softmax-invariant -> unused
    const float* Wo = (const float*)d_in[11];
    const float* bo = (const float*)d_in[12];

    char* ws = (char*)d_ws;
    u16*   q_ws = (u16*)(ws);               // 2 MB bf16 (b,h,c,d)
    u16*   k_ws = (u16*)(ws + (2 << 20));   // 2 MB bf16 (b,h,c,d)
    u16*   v_ws = (u16*)(ws + (4 << 20));   // 2 MB bf16 (b,h,c,d)
    float* a_ws = (float*)(ws + (6 << 20)); // 4 MB fp32 (b,c,D) attn output

    dim3 g(32, 8), blk(256);
    hipLaunchKernelGGL(gemm_qkvo, g, blk, 0, stream, x, Wq, bq, q_ws, (float*)nullptr, 0);
    hipLaunchKernelGGL(gemm_qkvo, g, blk, 0, stream, x, Wk, bk, k_ws, (float*)nullptr, 1);
    hipLaunchKernelGGL(gemm_qkvo, g, blk, 0, stream, x, Wv, bv, v_ws, (float*)nullptr, 2);
    hipLaunchKernelGGL(attn_kernel, dim3(4096), blk, 0, stream, q_ws, k_ws, v_ws, w1, b1, w2, a_ws);
    hipLaunchKernelGGL(gemm_qkvo, g, blk, 0, stream, a_ws, Wo, bo, (u16*)nullptr, (float*)d_out, 3);
}

// Round 6
// 634.346 us; speedup vs baseline: 1.4758x; 1.4758x over previous
//
#include <hip/hip_runtime.h>
#include <cstdint>

typedef unsigned short u16;
typedef __attribute__((ext_vector_type(8))) short short8;   // 8 bf16 (MFMA A/B frag)
typedef __attribute__((ext_vector_type(4))) float floatx4;  // MFMA C/D frag

__device__ __forceinline__ float b2f(u16 u) {
    union { unsigned int i; float f; } c; c.i = ((unsigned int)u) << 16; return c.f;
}
__device__ __forceinline__ u16 f2b(float f) {
    union { float f; unsigned int i; } c; c.f = f;
    unsigned int u = c.i;
    u = u + 0x7FFFu + ((u >> 16) & 1u);   // RNE
    return (u16)(u >> 16);
}
// tanh-gelu via exp2; max err vs exact erf-gelu ~3e-4
__device__ __forceinline__ float gelu_f(float x) {
    float u = x * x;
    float z = x * __builtin_fmaf(u, 0.1029432f, 2.3022082f);
    float t = __builtin_amdgcn_exp2f(z);
    float r = __builtin_amdgcn_rcpf(1.0f + t);
    return __builtin_fmaf(-x, r, x);
}

// ---------------------------------------------------------------------------
// GEMM: Y[m,n] = sum_k A[m,k]*W[n,k] + bias[n].  M=2048, N=512, K=512.
// A,W,bias fp32 (bf16-converted in staging for MFMA).
// mode 0: fp32 out, (b,h,c,dd) layout (q, v)
// mode 1: bf16 out, (b,h,c,dd) layout (k)
// mode 3: fp32 out, plain [m*512+n]   (final output)
// ---------------------------------------------------------------------------
__global__ __launch_bounds__(256) void gemm_qkvo(
    const float* __restrict__ A, const float* __restrict__ W, const float* __restrict__ bias,
    u16* __restrict__ outb, float* __restrict__ outf, int mode)
{
    __shared__ u16 xs[64 * 72];
    __shared__ u16 wsl[64 * 72];
    int tid = threadIdx.x;
    int lane = tid & 63;
    int wv = tid >> 6;
    int lo = lane & 15, hi = lane >> 4;
    int m0 = blockIdx.x * 64, n0 = blockIdx.y * 64;

    floatx4 acc[4];
#pragma unroll
    for (int mt = 0; mt < 4; ++mt) acc[mt] = (floatx4){0.f, 0.f, 0.f, 0.f};

    for (int k0 = 0; k0 < 512; k0 += 64) {
        __syncthreads();
#pragma unroll
        for (int i = 0; i < 2; ++i) {
            int v = tid + i * 256;
            int row = v >> 3, c8 = (v & 7) * 8;
            const float* ap = A + (m0 + row) * 512 + k0 + c8;
            const float* wp = W + (n0 + row) * 512 + k0 + c8;
            float4 a0 = *(const float4*)(ap);
            float4 a1 = *(const float4*)(ap + 4);
            float4 w0 = *(const float4*)(wp);
            float4 w1v = *(const float4*)(wp + 4);
            union { u16 u[8]; uint4 q; } ca, cw;
            ca.u[0] = f2b(a0.x); ca.u[1] = f2b(a0.y); ca.u[2] = f2b(a0.z); ca.u[3] = f2b(a0.w);
            ca.u[4] = f2b(a1.x); ca.u[5] = f2b(a1.y); ca.u[6] = f2b(a1.z); ca.u[7] = f2b(a1.w);
            cw.u[0] = f2b(w0.x); cw.u[1] = f2b(w0.y); cw.u[2] = f2b(w0.z); cw.u[3] = f2b(w0.w);
            cw.u[4] = f2b(w1v.x); cw.u[5] = f2b(w1v.y); cw.u[6] = f2b(w1v.z); cw.u[7] = f2b(w1v.w);
            *(uint4*)(xs + row * 72 + c8)  = ca.q;
            *(uint4*)(wsl + row * 72 + c8) = cw.q;
        }
        __syncthreads();
#pragma unroll
        for (int ks = 0; ks < 2; ++ks) {
            short8 bfr = *(const short8*)(wsl + (wv * 16 + lo) * 72 + ks * 32 + hi * 8);
#pragma unroll
            for (int mt = 0; mt < 4; ++mt) {
                short8 afr = *(const short8*)(xs + (mt * 16 + lo) * 72 + ks * 32 + hi * 8);
                acc[mt] = __builtin_amdgcn_mfma_f32_16x16x32_bf16(afr, bfr, acc[mt], 0, 0, 0);
            }
        }
    }

    int n = n0 + wv * 16 + lo;
    float bv = bias[n];
    int h = n >> 6, dd = n & 63;
#pragma unroll
    for (int mt = 0; mt < 4; ++mt) {
#pragma unroll
        for (int r = 0; r < 4; ++r) {
            int m = m0 + mt * 16 + hi * 4 + r;      // C/D: row=(lane>>4)*4+reg, col=lane&15
            float y = acc[mt][r] + bv;
            if (mode == 3) {
                outf[m * 512 + n] = y;
            } else {
                int b = m >> 10, c = m & 1023;
                int idx = (((b * 8 + h) * 1024) + c) * 64 + dd;
                if (mode == 1) outb[idx] = f2b(y);
                else           outf[idx] = y;
            }
        }
    }
}

// ---------------------------------------------------------------------------
// Fused second-order attention, v2 (barrier-free K-loop).
// 1 wave = 1 query. MFMA orientation: M = e (A = qw' in-register frags),
// N = j keys (B = k loaded straight from global as B-frags, no LDS).
// hid[e,j] = (qp[e]+b1[e]) + sum_dd qw'[e,dd]*k[j,dd],
//   qw'[e,dd] = q[dd]*w1qk[e,dd] + w1k[e,dd]  (kp fold).
// score[j] = sum_e gelu(hid)*w2[e]*0.125*log2e: in-lane over (mt,r) + 2 shuffles.
// Online softmax: global max (4 shuffles/iter), per-lane partial l (end-reduce),
// p broadcast via tiny per-wave LDS patch; PV reads v fp32 from global (L2).
// ---------------------------------------------------------------------------
__global__ __launch_bounds__(256, 3) void attn2(
    const float* __restrict__ qf, const u16* __restrict__ kb, const float* __restrict__ vf,
    const float* __restrict__ w1, const float* __restrict__ b1, const float* __restrict__ w2,
    float* __restrict__ ao)
{
    __shared__ float q_l[4 * 64];
    __shared__ float p_l[4 * 32];
    int tid = threadIdx.x;
    int lane = tid & 63;
    int wv = tid >> 6;
    int lo = lane & 15, hi = lane >> 4;
    int bh = blockIdx.x >> 8;                      // 0..15 = b*8+h
    int qi = ((blockIdx.x & 255) << 2) | wv;       // query 0..1023

    q_l[wv * 64 + lane] = qf[(bh * 1024 + qi) * 64 + lane];

    // qp[e]+b1[e] at lane=e
    float qpacc = b1[lane];
#pragma unroll
    for (int d8 = 0; d8 < 64; d8 += 8) {
        float4 wa = *(const float4*)(w1 + lane * 192 + d8);
        float4 wb = *(const float4*)(w1 + lane * 192 + d8 + 4);
        const float* q8 = q_l + wv * 64 + d8;      // wave-uniform broadcast reads
        qpacc = __builtin_fmaf(q8[0], wa.x, qpacc);
        qpacc = __builtin_fmaf(q8[1], wa.y, qpacc);
        qpacc = __builtin_fmaf(q8[2], wa.z, qpacc);
        qpacc = __builtin_fmaf(q8[3], wa.w, qpacc);
        qpacc = __builtin_fmaf(q8[4], wb.x, qpacc);
        qpacc = __builtin_fmaf(q8[5], wb.y, qpacc);
        qpacc = __builtin_fmaf(q8[6], wb.z, qpacc);
        qpacc = __builtin_fmaf(q8[7], wb.w, qpacc);
    }
    // rearrange to C/D-row indexing: e = mt*16 + hi*4 + r
    float qpb[4][4], w2c[4][4];
    float w2row = w2[lane] * 0.18033688f;          // w2[e] * (1/8) * log2(e)
#pragma unroll
    for (int mt = 0; mt < 4; ++mt)
#pragma unroll
        for (int r = 0; r < 4; ++r) {
            int e = mt * 16 + hi * 4 + r;
            qpb[mt][r] = __shfl(qpacc, e);
            w2c[mt][r] = __shfl(w2row, e);
        }

    // q pieces for frag build: qv2[ks][j] = q[ks*32 + hi*8 + j]
    float qv2[2][8];
#pragma unroll
    for (int ks = 0; ks < 2; ++ks)
#pragma unroll
        for (int j = 0; j < 8; ++j)
            qv2[ks][j] = q_l[wv * 64 + ks * 32 + hi * 8 + j];

    // A-frags: qw'[e = mt*16+lo][dd = ks*32 + hi*8 + j], bf16
    short8 af[4][2];
#pragma unroll
    for (int mt = 0; mt < 4; ++mt) {
        const float* wr = w1 + (mt * 16 + lo) * 192;
#pragma unroll
        for (int ks = 0; ks < 2; ++ks) {
            int dd0 = ks * 32 + hi * 8;
            float4 a0 = *(const float4*)(wr + 128 + dd0);
            float4 a1 = *(const float4*)(wr + 128 + dd0 + 4);
            float4 k0 = *(const float4*)(wr + 64 + dd0);
            float4 k1 = *(const float4*)(wr + 64 + dd0 + 4);
            union { u16 u[8]; short8 s; } cv;
            cv.u[0] = f2b(__builtin_fmaf(qv2[ks][0], a0.x, k0.x));
            cv.u[1] = f2b(__builtin_fmaf(qv2[ks][1], a0.y, k0.y));
            cv.u[2] = f2b(__builtin_fmaf(qv2[ks][2], a0.z, k0.z));
            cv.u[3] = f2b(__builtin_fmaf(qv2[ks][3], a0.w, k0.w));
            cv.u[4] = f2b(__builtin_fmaf(qv2[ks][4], a1.x, k1.x));
            cv.u[5] = f2b(__builtin_fmaf(qv2[ks][5], a1.y, k1.y));
            cv.u[6] = f2b(__builtin_fmaf(qv2[ks][6], a1.z, k1.z));
            cv.u[7] = f2b(__builtin_fmaf(qv2[ks][7], a1.w, k1.w));
            af[mt][ks] = cv.s;
        }
    }

    float m_run = -1e30f, l_run = 0.f;
    float oa0 = 0.f, oa1 = 0.f, oa2 = 0.f, oa3 = 0.f;
    const u16*   kbase = kb + bh * 65536;
    const float* vbase = vf + bh * 65536;

    for (int j0 = 0; j0 < 1024; j0 += 32) {
        // B-frags direct from global: k[j = j0 + t*16 + lo][dd = ks*32 + hi*8]
        short8 bf[2][2];
#pragma unroll
        for (int t = 0; t < 2; ++t)
#pragma unroll
            for (int ks = 0; ks < 2; ++ks) {
                uint4 kv = *(const uint4*)(kbase + (j0 + t * 16 + lo) * 64 + ks * 32 + hi * 8);
                bf[t][ks] = *(short8*)&kv;
            }

        floatx4 acc[4][2];
#pragma unroll
        for (int mt = 0; mt < 4; ++mt)
#pragma unroll
            for (int t = 0; t < 2; ++t)
                acc[mt][t] = (floatx4){qpb[mt][0], qpb[mt][1], qpb[mt][2], qpb[mt][3]};
#pragma unroll
        for (int ks = 0; ks < 2; ++ks)
#pragma unroll
            for (int mt = 0; mt < 4; ++mt)
#pragma unroll
                for (int t = 0; t < 2; ++t)
                    acc[mt][t] = __builtin_amdgcn_mfma_f32_16x16x32_bf16(af[mt][ks], bf[t][ks], acc[mt][t], 0, 0, 0);

        // score[j]: in-lane e-partials (mt,r) then 2 shuffles over row-groups
        float s0 = 0.f, s1 = 0.f;
#pragma unroll
        for (int mt = 0; mt < 4; ++mt)
#pragma unroll
            for (int r = 0; r < 4; ++r) {
                s0 = __builtin_fmaf(gelu_f(acc[mt][0][r]), w2c[mt][r], s0);
                s1 = __builtin_fmaf(gelu_f(acc[mt][1][r]), w2c[mt][r], s1);
            }
        s0 += __shfl_xor(s0, 16); s0 += __shfl_xor(s0, 32);   // s[j=lo]
        s1 += __shfl_xor(s1, 16); s1 += __shfl_xor(s1, 32);   // s[j=16+lo]

        float tm = fmaxf(s0, s1);
        tm = fmaxf(tm, __shfl_xor(tm, 1));
        tm = fmaxf(tm, __shfl_xor(tm, 2));
        tm = fmaxf(tm, __shfl_xor(tm, 4));
        tm = fmaxf(tm, __shfl_xor(tm, 8));
        float m_new = fmaxf(m_run, tm);
        float alpha = __builtin_amdgcn_exp2f(m_run - m_new);
        float p0 = __builtin_amdgcn_exp2f(s0 - m_new);
        float p1 = __builtin_amdgcn_exp2f(s1 - m_new);
        l_run = __builtin_fmaf(l_run, alpha, p0 + p1);   // per-lane partial (over lo)
        oa0 *= alpha; oa1 *= alpha; oa2 *= alpha; oa3 *= alpha;
        m_run = m_new;

        if (lane < 16) {
            p_l[wv * 32 + lane] = p0;
            p_l[wv * 32 + 16 + lane] = p1;
        }
        // PV: v fp32 from global (coalesced 256B rows, L2-resident)
        const float* vrow = vbase + j0 * 64 + lane;
#pragma unroll
        for (int q4 = 0; q4 < 8; ++q4) {
            float4 pr = *(const float4*)(p_l + wv * 32 + q4 * 4);
            oa0 = __builtin_fmaf(pr.x, vrow[(q4 * 4 + 0) * 64], oa0);
            oa1 = __builtin_fmaf(pr.y, vrow[(q4 * 4 + 1) * 64], oa1);
            oa2 = __builtin_fmaf(pr.z, vrow[(q4 * 4 + 2) * 64], oa2);
            oa3 = __builtin_fmaf(pr.w, vrow[(q4 * 4 + 3) * 64], oa3);
        }
    }

    float l = l_run;
    l += __shfl_xor(l, 1); l += __shfl_xor(l, 2);
    l += __shfl_xor(l, 4); l += __shfl_xor(l, 8);
    float outv = (oa0 + oa1 + oa2 + oa3) * __builtin_amdgcn_rcpf(l);
    int b = bh >> 3, h = bh & 7;
    ao[(b * 1024 + qi) * 512 + h * 64 + lane] = outv;   // (B,C,D) fp32
}

// ---------------------------------------------------------------------------
extern "C" void kernel_launch(void* const* d_in, const int* in_sizes, int n_in,
                              void* d_out, int out_size, void* d_ws, size_t ws_size,
                              hipStream_t stream)
{
    (void)in_sizes; (void)n_in; (void)out_size; (void)ws_size;
    const float* x  = (const float*)d_in[0];
    const float* Wq = (const float*)d_in[1];
    const float* bq = (const float*)d_in[2];
    const float* Wk = (const float*)d_in[3];
    const float* bk = (const float*)d_in[4];
    const float* Wv = (const float*)d_in[5];
    const float* bv = (const float*)d_in[6];
    const float* w1 = (const float*)d_in[7];
    const float* b1 = (const float*)d_in[8];
    const float* w2 = (const float*)d_in[9];
    // d_in[10] = b2: scalar shift of all scores -> softmax-invariant -> unused
    const float* Wo = (const float*)d_in[11];
    const float* bo = (const float*)d_in[12];

    char* ws = (char*)d_ws;
    float* q_ws = (float*)(ws);               // 4 MB fp32 (b,h,c,d)
    u16*   k_ws = (u16*)(ws + (4u << 20));    // 2 MB bf16 (b,h,c,d)
    float* v_ws = (float*)(ws + (6u << 20));  // 4 MB fp32 (b,h,c,d)
    float* a_ws = (float*)(ws + (10u << 20)); // 4 MB fp32 (b,c,D)

    dim3 g(32, 8), blk(256);
    hipLaunchKernelGGL(gemm_qkvo, g, blk, 0, stream, x, Wq, bq, (u16*)nullptr, q_ws, 0);
    hipLaunchKernelGGL(gemm_qkvo, g, blk, 0, stream, x, Wk, bk, k_ws, (float*)nullptr, 1);
    hipLaunchKernelGGL(gemm_qkvo, g, blk, 0, stream, x, Wv, bv, (u16*)nullptr, v_ws, 0);
    hipLaunchKernelGGL(attn2, dim3(4096), blk, 0, stream, q_ws, k_ws, v_ws, w1, b1, w2, a_ws);
    hipLaunchKernelGGL(gemm_qkvo, g, blk, 0, stream, a_ws, Wo, bo, (u16*)nullptr, (float*)d_out, 3);
}